// Round 1
// baseline (104.576 us; speedup 1.0000x reference)
//
#include <hip/hip_runtime.h>
#include <math.h>

#define B_N 524288
#define C_N 40
constexpr int BLOCK = 320;   // 5 waves; 320*4 floats = 1280 = 32 full rows of C=40
constexpr int GRID  = 2048;
constexpr int VEC   = 4;

// Single fused pass: per-class {cnt_pos, S_pos, S_pos_easy, S_neg, S_neg_easy}.
// Each thread owns 4 fixed classes (tile stride is a multiple of C), accumulates
// in registers, then LDS-atomic reduce, then one global atomic per LDS slot.
__global__ __launch_bounds__(BLOCK) void bdl_accum(
    const float* __restrict__ pred, const float* __restrict__ tgt,
    float* __restrict__ gacc)
{
    float cntp[VEC] = {0.f, 0.f, 0.f, 0.f};
    float sp[VEC]   = {0.f, 0.f, 0.f, 0.f};
    float spe[VEC]  = {0.f, 0.f, 0.f, 0.f};
    float sn[VEC]   = {0.f, 0.f, 0.f, 0.f};
    float sne[VEC]  = {0.f, 0.f, 0.f, 0.f};

    const int tid = threadIdx.x;
    const size_t total  = (size_t)B_N * C_N;
    const size_t stride = (size_t)gridDim.x * BLOCK * VEC;

    for (size_t i = (size_t)blockIdx.x * (BLOCK * VEC) + (size_t)tid * VEC;
         i < total; i += stride) {
        const float4 p = *reinterpret_cast<const float4*>(pred + i);
        const float4 t = *reinterpret_cast<const float4*>(tgt + i);
        const float px[4] = {p.x, p.y, p.z, p.w};
        const float tx[4] = {t.x, t.y, t.z, t.w};
        #pragma unroll
        for (int j = 0; j < VEC; ++j) {
            const float x  = px[j];
            const float tv = tx[j];
            const float ax = fabsf(x);
            const float e  = __expf(-ax);                    // exp(-|x|) in (0,1]
            const float bce = fmaxf(x, 0.f) - x * tv + log1pf(e);
            const float s   = (x >= 0.f) ? (1.f / (1.f + e)) // sigmoid(x)
                                         : (e / (1.f + e));
            cntp[j] += tv;
            if (tv != 0.f) {
                sp[j] += bce;
                if (s > 0.9f) spe[j] += bce;   // g = 1-s < 0.1 (easy positive)
            } else {
                sn[j] += bce;
                if (s < 0.1f) sne[j] += bce;   // g = s < 0.1   (easy negative)
            }
        }
    }

    __shared__ float lacc[C_N * 5];
    if (tid < C_N * 5) lacc[tid] = 0.f;
    __syncthreads();
    const int c0 = (tid * VEC) % C_N;          // constant classes per thread
    #pragma unroll
    for (int j = 0; j < VEC; ++j) {
        float* a = &lacc[(c0 + j) * 5];
        atomicAdd(a + 0, cntp[j]);
        atomicAdd(a + 1, sp[j]);
        atomicAdd(a + 2, spe[j]);
        atomicAdd(a + 3, sn[j]);
        atomicAdd(a + 4, sne[j]);
    }
    __syncthreads();
    if (tid < C_N * 5) atomicAdd(&gacc[tid], lacc[tid]);
}

__global__ void bdl_final(const float* __restrict__ gacc, float* __restrict__ out)
{
    const int c = threadIdx.x;
    const float Bf  = (float)B_N;
    const float bal = 0.5f * Bf;               // PROP * batch
    float contrib = 0.f;
    if (c < C_N) {
        const float cntp = gacc[c * 5 + 0];
        const float sp   = gacc[c * 5 + 1];
        const float spe  = gacc[c * 5 + 2];
        const float sn   = gacc[c * 5 + 3];
        const float sne  = gacc[c * 5 + 4];
        const bool posmaj = (cntp >= bal);     // pos_gt; else neg_gt (exclusive)
        const float nmaj = posmaj ? cntp : (Bf - cntp);
        const float nmin = Bf - nmaj;
        const float smaj = posmaj ? (sp - spe) : (sn - sne);
        const float smin = posmaj ? sn : sp;
        const float wmaj = bal / fmaxf(nmaj, 1.f);
        const float wmin = (nmin > 0.f) ? ((Bf - bal) / fmaxf(nmin, 1.f)) : 1.f;
        contrib = smaj * wmaj + smin * wmin;
    }
    #pragma unroll
    for (int o = 32; o > 0; o >>= 1) contrib += __shfl_down(contrib, o);
    if (c == 0) out[0] = contrib / (Bf * (float)C_N);
}

extern "C" void kernel_launch(void* const* d_in, const int* in_sizes, int n_in,
                              void* d_out, int out_size, void* d_ws, size_t ws_size,
                              hipStream_t stream) {
    const float* pred = (const float*)d_in[0];
    const float* tgt  = (const float*)d_in[1];
    float* gacc = (float*)d_ws;                       // 200 floats of scratch
    hipMemsetAsync(gacc, 0, C_N * 5 * sizeof(float), stream);
    bdl_accum<<<GRID, BLOCK, 0, stream>>>(pred, tgt, gacc);
    bdl_final<<<1, 64, 0, stream>>>(gacc, (float*)d_out);
}

// Round 2
// 94.220 us; speedup vs baseline: 1.1099x; 1.1099x over previous
//
#include <hip/hip_runtime.h>
#include <math.h>

#define B_N 524288
#define C_N 40
constexpr int BLOCK = 320;   // 5 waves; 320*4 floats = 1280 = 32 full rows of C=40
constexpr int GRID  = 2048;
constexpr int VEC   = 4;

// Single fused pass, branchless. Per-class scalars:
//   cntp = sum(t), s_all = sum(bce), s_pos = sum(t*bce),
//   spe = sum(bce | t=1 & x>ln9)  (easy positives: g=1-s<0.1),
//   sne = sum(bce | t=0 & x<-ln9) (easy negatives: g=s<0.1).
// Sigmoid thresholds replaced by logit-space compares: s>0.9 <=> x>ln9.
__global__ __launch_bounds__(BLOCK) void bdl_accum(
    const float* __restrict__ pred, const float* __restrict__ tgt,
    float* __restrict__ gacc)
{
    constexpr float LN9 = 2.1972245773362196f;

    float cntp[VEC] = {0.f, 0.f, 0.f, 0.f};
    float sall[VEC] = {0.f, 0.f, 0.f, 0.f};
    float spos[VEC] = {0.f, 0.f, 0.f, 0.f};
    float spe[VEC]  = {0.f, 0.f, 0.f, 0.f};
    float sne[VEC]  = {0.f, 0.f, 0.f, 0.f};

    const int tid = threadIdx.x;
    const size_t total  = (size_t)B_N * C_N;
    const size_t stride = (size_t)gridDim.x * BLOCK * VEC;

    for (size_t i = (size_t)blockIdx.x * (BLOCK * VEC) + (size_t)tid * VEC;
         i < total; i += stride) {
        const float4 p = *reinterpret_cast<const float4*>(pred + i);
        const float4 t = *reinterpret_cast<const float4*>(tgt + i);
        const float px[4] = {p.x, p.y, p.z, p.w};
        const float tx[4] = {t.x, t.y, t.z, t.w};
        #pragma unroll
        for (int j = 0; j < VEC; ++j) {
            const float x  = px[j];
            const float tv = tx[j];
            const float ax = fabsf(x);
            const float e  = __expf(-ax);                 // v_exp path
            const float sp_ = __logf(1.f + e);            // softplus(-|x|), v_log path
            const float bce = sp_ + fmaxf(x, 0.f) - x * tv;
            const float bpos = (x >  LN9) ? bce : 0.f;    // easy if positive
            const float bneg = (x < -LN9) ? bce : 0.f;    // easy if negative
            cntp[j] += tv;
            sall[j] += bce;
            spos[j]  = fmaf(tv, bce,   spos[j]);
            spe[j]   = fmaf(tv, bpos,  spe[j]);           // t * easy-pos
            sne[j]   = fmaf(-tv, bneg, sne[j] + bneg);    // (1-t) * easy-neg
        }
    }

    __shared__ float lacc[C_N * 5];
    if (tid < C_N * 5) lacc[tid] = 0.f;
    __syncthreads();
    const int c0 = (tid * VEC) % C_N;          // constant classes per thread
    #pragma unroll
    for (int j = 0; j < VEC; ++j) {
        float* a = &lacc[(c0 + j) * 5];
        atomicAdd(a + 0, cntp[j]);
        atomicAdd(a + 1, sall[j]);
        atomicAdd(a + 2, spos[j]);
        atomicAdd(a + 3, spe[j]);
        atomicAdd(a + 4, sne[j]);
    }
    __syncthreads();
    if (tid < C_N * 5) atomicAdd(&gacc[tid], lacc[tid]);
}

__global__ void bdl_final(const float* __restrict__ gacc, float* __restrict__ out)
{
    const int c = threadIdx.x;
    const float Bf  = (float)B_N;
    const float bal = 0.5f * Bf;               // PROP * batch
    float contrib = 0.f;
    if (c < C_N) {
        const float cntp = gacc[c * 5 + 0];
        const float sall = gacc[c * 5 + 1];
        const float sp   = gacc[c * 5 + 2];
        const float spe  = gacc[c * 5 + 3];
        const float sne  = gacc[c * 5 + 4];
        const float sn   = sall - sp;
        const bool posmaj = (cntp >= bal);     // pos_gt; else neg_gt (exclusive)
        const float nmaj = posmaj ? cntp : (Bf - cntp);
        const float nmin = Bf - nmaj;
        const float smaj = posmaj ? (sp - spe) : (sn - sne);
        const float smin = posmaj ? sn : sp;
        const float wmaj = bal / fmaxf(nmaj, 1.f);
        const float wmin = (nmin > 0.f) ? ((Bf - bal) / fmaxf(nmin, 1.f)) : 1.f;
        contrib = smaj * wmaj + smin * wmin;
    }
    #pragma unroll
    for (int o = 32; o > 0; o >>= 1) contrib += __shfl_down(contrib, o);
    if (c == 0) out[0] = contrib / (Bf * (float)C_N);
}

extern "C" void kernel_launch(void* const* d_in, const int* in_sizes, int n_in,
                              void* d_out, int out_size, void* d_ws, size_t ws_size,
                              hipStream_t stream) {
    const float* pred = (const float*)d_in[0];
    const float* tgt  = (const float*)d_in[1];
    float* gacc = (float*)d_ws;                       // 200 floats of scratch
    hipMemsetAsync(gacc, 0, C_N * 5 * sizeof(float), stream);
    bdl_accum<<<GRID, BLOCK, 0, stream>>>(pred, tgt, gacc);
    bdl_final<<<1, 64, 0, stream>>>(gacc, (float*)d_out);
}

// Round 3
// 65.648 us; speedup vs baseline: 1.5930x; 1.4352x over previous
//
#include <hip/hip_runtime.h>
#include <math.h>

#define B_N 524288
#define C_N 40
constexpr int BLOCK  = 320;   // 5 waves; 320*4 = 1280 floats = 32 rows of C=40
constexpr int VEC    = 4;
constexpr int UNROLL = 4;     // 4 independent float4-pairs in flight per thread
constexpr int GRID   = 1024;  // total/(GRID*BLOCK*VEC*UNROLL) = exactly 4 iters
constexpr int NREP   = 32;    // accumulator replicas to spread atomic contention

// Single fused pass, branchless, 4x-unrolled for memory-level parallelism.
// Per-class scalars: cntp=sum(t), s_all=sum(bce), s_pos=sum(t*bce),
//   spe=sum(bce | t=1 & x>ln9), sne=sum(bce | t=0 & x<-ln9).
// Unroll offsets u*1280 are multiples of C=40, so each thread's 4 classes are
// invariant across both unroll slots and grid-stride iterations.
__global__ __launch_bounds__(BLOCK) void bdl_accum(
    const float* __restrict__ pred, const float* __restrict__ tgt,
    float* __restrict__ gacc)
{
    constexpr float LN9 = 2.1972245773362196f;

    float cntp[VEC] = {0.f, 0.f, 0.f, 0.f};
    float sall[VEC] = {0.f, 0.f, 0.f, 0.f};
    float spos[VEC] = {0.f, 0.f, 0.f, 0.f};
    float spe[VEC]  = {0.f, 0.f, 0.f, 0.f};
    float sne[VEC]  = {0.f, 0.f, 0.f, 0.f};

    const int tid = threadIdx.x;
    const size_t total  = (size_t)B_N * C_N;
    const size_t tile   = (size_t)BLOCK * VEC * UNROLL;          // 5120
    const size_t stride = (size_t)GRID * tile;

    for (size_t base = (size_t)blockIdx.x * tile + (size_t)tid * VEC;
         base < total; base += stride) {
        float4 p[UNROLL], t[UNROLL];
        #pragma unroll
        for (int u = 0; u < UNROLL; ++u) {
            p[u] = *reinterpret_cast<const float4*>(pred + base + (size_t)u * (BLOCK * VEC));
            t[u] = *reinterpret_cast<const float4*>(tgt  + base + (size_t)u * (BLOCK * VEC));
        }
        #pragma unroll
        for (int u = 0; u < UNROLL; ++u) {
            const float px[4] = {p[u].x, p[u].y, p[u].z, p[u].w};
            const float tx[4] = {t[u].x, t[u].y, t[u].z, t[u].w};
            #pragma unroll
            for (int j = 0; j < VEC; ++j) {
                const float x  = px[j];
                const float tv = tx[j];
                const float e  = __expf(-fabsf(x));
                const float sp_ = __logf(1.f + e);            // softplus(-|x|)
                const float bce = sp_ + fmaxf(x, 0.f) - x * tv;
                const float bpos = (x >  LN9) ? bce : 0.f;    // easy positive
                const float bneg = (x < -LN9) ? bce : 0.f;    // easy negative
                cntp[j] += tv;
                sall[j] += bce;
                spos[j]  = fmaf(tv, bce,   spos[j]);
                spe[j]   = fmaf(tv, bpos,  spe[j]);           // t * easy-pos
                sne[j]   = fmaf(-tv, bneg, sne[j] + bneg);    // (1-t) * easy-neg
            }
        }
    }

    __shared__ float lacc[C_N * 5];
    if (tid < C_N * 5) lacc[tid] = 0.f;
    __syncthreads();
    const int c0 = (tid * VEC) % C_N;          // constant classes per thread
    #pragma unroll
    for (int j = 0; j < VEC; ++j) {
        float* a = &lacc[(c0 + j) * 5];
        atomicAdd(a + 0, cntp[j]);
        atomicAdd(a + 1, sall[j]);
        atomicAdd(a + 2, spos[j]);
        atomicAdd(a + 3, spe[j]);
        atomicAdd(a + 4, sne[j]);
    }
    __syncthreads();
    if (tid < C_N * 5)
        atomicAdd(&gacc[(blockIdx.x % NREP) * (C_N * 5) + tid], lacc[tid]);
}

__global__ void bdl_final(const float* __restrict__ gacc, float* __restrict__ out)
{
    __shared__ float acc[C_N * 5];
    const int tid = threadIdx.x;
    if (tid < C_N * 5) {
        float s = 0.f;
        #pragma unroll
        for (int r = 0; r < NREP; ++r) s += gacc[r * (C_N * 5) + tid];
        acc[tid] = s;
    }
    __syncthreads();
    if (tid == 0) {
        const float Bf  = (float)B_N;
        const float bal = 0.5f * Bf;               // PROP * batch
        float tot = 0.f;
        for (int c = 0; c < C_N; ++c) {
            const float cntp = acc[c * 5 + 0];
            const float sall = acc[c * 5 + 1];
            const float sp   = acc[c * 5 + 2];
            const float spe  = acc[c * 5 + 3];
            const float sne  = acc[c * 5 + 4];
            const float sn   = sall - sp;
            const bool posmaj = (cntp >= bal);     // pos_gt; else neg_gt
            const float nmaj = posmaj ? cntp : (Bf - cntp);
            const float nmin = Bf - nmaj;
            const float smaj = posmaj ? (sp - spe) : (sn - sne);
            const float smin = posmaj ? sn : sp;
            const float wmaj = bal / fmaxf(nmaj, 1.f);
            const float wmin = (nmin > 0.f) ? ((Bf - bal) / fmaxf(nmin, 1.f)) : 1.f;
            tot += smaj * wmaj + smin * wmin;
        }
        out[0] = tot / (Bf * (float)C_N);
    }
}

extern "C" void kernel_launch(void* const* d_in, const int* in_sizes, int n_in,
                              void* d_out, int out_size, void* d_ws, size_t ws_size,
                              hipStream_t stream) {
    const float* pred = (const float*)d_in[0];
    const float* tgt  = (const float*)d_in[1];
    float* gacc = (float*)d_ws;                       // NREP*200 floats = 25.6 KB
    hipMemsetAsync(gacc, 0, NREP * C_N * 5 * sizeof(float), stream);
    bdl_accum<<<GRID, BLOCK, 0, stream>>>(pred, tgt, gacc);
    bdl_final<<<1, 256, 0, stream>>>(gacc, (float*)d_out);
}